// Round 2
// baseline (1040.516 us; speedup 1.0000x reference)
//
#include <hip/hip_runtime.h>
#include <hip/hip_bf16.h>
#include <cmath>
#include <complex>

#define TPB 256
#define SUBS 8
#define EPG 4
#define NM 115
#define NW3J 363

// ---------------- host-side W3J construction (exact port of reference) ------
namespace {

double fct(int n){ double r=1; for(int i=2;i<=n;i++) r*=i; return r; }

double su2_cg(int j1,int j2,int j3,int m1,int m2,int m3){
  if(m1+m2!=m3) return 0.0;
  double pref = std::sqrt((2*j3+1)*fct(j1+j2-j3)*fct(j1-j2+j3)*fct(-j1+j2+j3)/fct(j1+j2+j3+1));
  pref *= std::sqrt(fct(j3+m3)*fct(j3-m3)*fct(j1-m1)*fct(j1+m1)*fct(j2-m2)*fct(j2+m2));
  double s=0;
  for(int k=0;k<=j1+j2-j3;k++){
    int d0=k, d1=j1+j2-j3-k, d2=j1-m1-k, d3=j2+m2-k, d4=j3-j2+m1+k, d5=j3-j1-m2+k;
    if(d0<0||d1<0||d2<0||d3<0||d4<0||d5<0) continue;
    double t = 1.0/(fct(d0)*fct(d1)*fct(d2)*fct(d3)*fct(d4)*fct(d5));
    s += (k&1)? -t : t;
  }
  return pref*s;
}

typedef std::complex<double> cd;

void qmat(int l, cd q[5][5]){
  for(int i=0;i<5;i++) for(int j=0;j<5;j++) q[i][j] = cd(0,0);
  const double is2 = 1.0/std::sqrt(2.0);
  for(int m=-l;m<0;m++){ q[l+m][l-m] = cd(is2,0); q[l+m][l+m] = cd(0,-is2); }
  q[l][l] = cd(1,0);
  for(int m=1;m<=l;m++){ double sg = (m&1)? -1.0: 1.0; q[l+m][l+m] = cd(sg*is2,0); q[l+m][l-m] = cd(0, sg*is2); }
  cd ph(1,0), mi(0,-1);
  for(int t=0;t<l;t++) ph *= mi;
  for(int i=0;i<5;i++) for(int j=0;j<5;j++) q[i][j] *= ph;
}

void w3j_calc(int l1,int l2,int l3,double* out){
  int n1=2*l1+1,n2=2*l2+1,n3=2*l3+1;
  double C[5][5][5] = {};
  for(int m1=-l1;m1<=l1;m1++)for(int m2=-l2;m2<=l2;m2++)for(int m3=-l3;m3<=l3;m3++)
    C[l1+m1][l2+m2][l3+m3] = su2_cg(l1,l2,l3,m1,m2,m3);
  cd q1[5][5], q2[5][5], q3[5][5];
  qmat(l1,q1); qmat(l2,q2); qmat(l3,q3);
  double wr[125], wi[125];
  double nr=0, ni=0;
  for(int a=0;a<n1;a++)for(int b=0;b<n2;b++)for(int c=0;c<n3;c++){
    cd s(0,0);
    for(int i=0;i<n1;i++)for(int k=0;k<n2;k++)for(int m=0;m<n3;m++)
      s += q1[i][a]*q2[k][b]*std::conj(q3[m][c])*C[i][k][m];
    int idx = (a*n2+b)*n3+c;
    wr[idx]=s.real(); wi[idx]=s.imag();
    nr += s.real()*s.real(); ni += s.imag()*s.imag();
  }
  bool useR = std::sqrt(nr) >= std::sqrt(ni);
  double nn = std::sqrt(useR? nr: ni);
  for(int q=0;q<n1*n2*n3;q++) out[q] = (useR? wr[q]: wi[q])/nn;
}

struct UploadArg {
  float w3j[NW3J];        // PATH_W premultiplied, dense per path
  unsigned int meta[NM];  // per M-entry: woff | nc<<10 | nb<<14 | boff<<18
};

UploadArg g_upload;

struct BuildInit {
  BuildInit(){
    const int P[11][3] = {{0,0,0},{0,1,1},{0,2,2},{1,0,1},{1,1,0},{1,1,2},
                          {1,2,1},{2,0,2},{2,1,1},{2,2,0},{2,2,2}};
    const int cnt[3] = {3,4,4};
    const int AO[3] = {0,1,4};
    int off = 0, t = 0;
    for(int p=0;p<11;p++){
      int i=P[p][0], j=P[p][1], k=P[p][2];
      int na=2*i+1, nb=2*j+1, nc=2*k+1;
      double W[125];
      w3j_calc(i,j,k,W);
      double pw = std::sqrt((2.0*k+1.0)/(double)cnt[k]);
      for(int q=0;q<na*nb*nc;q++) g_upload.w3j[off+q] = (float)(W[q]*pw);
      for(int a=0;a<na;a++)
        for(int c=0;c<nc;c++)
          g_upload.meta[t++] = (unsigned)((off + a*nb*nc + c) | (nc<<10) | (nb<<14) | (AO[j]<<18));
      off += na*nb*nc;
    }
  }
};
BuildInit g_build_init;

} // namespace

// ---------------- device kernel --------------------------------------------

__global__ __launch_bounds__(TPB) void edge_kernel(
    const float* __restrict__ nodes,
    const float* __restrict__ pos,
    const int* __restrict__ src,
    const int* __restrict__ dst,
    const float* __restrict__ w1,
    const float* __restrict__ b1,
    const float* __restrict__ w2,
    const float* __restrict__ b2,
    float* __restrict__ outp,
    int E,
    UploadArg up)
{
  __shared__ float s_w3j[NW3J];
  __shared__ float s_y[SUBS][EPG][12];
  __shared__ float s_h[SUBS][64][EPG];
  __shared__ float s_M[SUBS][EPG][NM+1];

  const int tid = threadIdx.x;
  const int u = tid & 31;
  const int sub = tid >> 5;

  for(int t = tid; t < NW3J; t += TPB) s_w3j[t] = up.w3j[t];

  const long ebase = ((long)blockIdx.x * SUBS + sub) * EPG;
  float bes[EPG][8];
  float cut[EPG];
  int vsrc[EPG], vdst[EPG];
  bool valid[EPG];

  #pragma unroll
  for(int e=0;e<EPG;e++){
    long eg = ebase + e;
    bool v = (eg < (long)E);
    valid[e] = v;
    int se = v ? src[eg] : 0;
    int de = v ? dst[eg] : 0;
    vsrc[e] = se; vdst[e] = de;
    float px = pos[se*3+0] - pos[de*3+0];
    float py = pos[se*3+1] - pos[de*3+1];
    float pz = pos[se*3+2] - pos[de*3+2];
    float d2 = px*px + py*py + pz*pz;
    float d = sqrtf(d2);
    float inv = 1.0f / fmaxf(d, 1e-12f);
    float x = px*inv, y = py*inv, z = pz*inv;
    float yv[9];
    yv[0] = 1.0f;
    yv[1] = 1.7320508075688772f*y;
    yv[2] = 1.7320508075688772f*z;
    yv[3] = 1.7320508075688772f*x;
    yv[4] = 3.872983346207417f*x*y;
    yv[5] = 3.872983346207417f*y*z;
    yv[6] = 1.118033988749895f*(3.0f*z*z - 1.0f);
    yv[7] = 3.872983346207417f*x*z;
    yv[8] = 1.9364916731037085f*(x*x - y*y);
    #pragma unroll
    for(int q=0;q<9;q++) s_y[sub][e][q] = yv[q];  // all lanes write same value
    // bessel basis via sin recurrence: s_{n+1} = 2cos(a) s_n - s_{n-1}
    float tt = d * 0.2f;
    float st = (tt > 0.0f) ? tt : 1.0f;
    float msk = (tt > 0.0f && tt < 1.0f) ? 1.0f : 0.0f;
    float ang = 3.14159265358979323846f * tt;
    float s1 = __sinf(ang), c1 = __cosf(ang);
    float kk = 0.6324555320336759f * msk / st;   // sqrt(2/5)
    float c2 = 2.0f*c1;
    float sp = 0.0f, sc = s1;
    bes[e][0] = kk*s1;
    #pragma unroll
    for(int n=1;n<8;n++){ float sn = c2*sc - sp; sp = sc; sc = sn; bes[e][n] = kk*sn; }
    // polynomial cutoff
    float uu = d*0.25f;
    float u2 = uu*uu;
    float u5 = u2*u2*uu;
    float env = 1.0f - 6.0f*u5 + 5.0f*u5*uu;
    cut[e] = (d < 4.0f) ? env : 0.0f;
  }

  // MLP1: thread u computes h[j] for j = u, u+32, all 4 edges -> LDS [sub][j][e]
  #pragma unroll
  for(int half=0; half<2; half++){
    int j = u + 32*half;
    float hb = b1[j];
    float wc[8];
    #pragma unroll
    for(int k=0;k<8;k++) wc[k] = w1[k*64 + j];
    float hh[EPG];
    #pragma unroll
    for(int e=0;e<EPG;e++){
      float a = hb;
      #pragma unroll
      for(int k=0;k<8;k++) a += bes[e][k]*wc[k];
      float sg = 1.0f/(1.0f + __expf(-a));
      hh[e] = a*sg;
    }
    float4 hv; hv.x = hh[0]; hv.y = hh[1]; hv.z = hh[2]; hv.w = hh[3];
    *(float4*)(&s_h[sub][j][0]) = hv;
  }
  __syncthreads();

  // Build M[a,c] = sum_b W3J[a,b,c] * y[b] per (sub,edge), cooperatively
  #pragma unroll
  for(int w=0; w<4; w++){
    int t = u + 32*w;
    if(t < NM){
      unsigned int md = up.meta[t];
      int woff = md & 1023;
      int nc   = (md>>10) & 15;
      int nb   = (md>>14) & 15;
      int boff = (md>>18) & 15;
      #pragma unroll
      for(int e=0;e<EPG;e++){
        float s = 0.0f;
        for(int b=0;b<nb;b++) s += s_w3j[woff + b*nc] * s_y[sub][e][boff + b];
        s_M[sub][e][t] = s;
      }
    }
  }
  __syncthreads();

  // MLP2: wacc[e][p] = sum_j h[e][j] * w2[j][p*32+u]
  float wacc[EPG][12];
  #pragma unroll
  for(int e=0;e<EPG;e++){
    #pragma unroll
    for(int p=0;p<12;p++) wacc[e][p] = 0.0f;
  }
  const float* wbase = w2 + u;
  for(int j=0;j<64;j++){
    float4 hv = *(const float4*)(&s_h[sub][j][0]);
    float sw[11];
    #pragma unroll
    for(int p=0;p<11;p++) sw[p] = wbase[j*352 + p*32];
    float hh[4]; hh[0]=hv.x; hh[1]=hv.y; hh[2]=hv.z; hh[3]=hv.w;
    #pragma unroll
    for(int e=0;e<EPG;e++){
      #pragma unroll
      for(int p=0;p<11;p++) wacc[e][p] += hh[e]*sw[p];
    }
  }

  // Tensor product + atomic scatter (scaled by 1/sqrt(25) = 0.2)
  constexpr int PI_[11]   = {0,0,0,1,1,1,1,2,2,2,2};
  constexpr int PK_[11]   = {0,1,2,1,0,2,1,2,1,0,2};
  constexpr int TOFF_[11] = {0,1,4,9,18,21,36,45,70,85,90};
  constexpr int AO_[3]    = {0,1,4};

  #pragma unroll
  for(int e=0;e<EPG;e++){
    if(!valid[e]) continue;
    const float* nr = nodes + (long)vsrc[e]*288;
    float xv[9];
    xv[0] = nr[u];
    #pragma unroll
    for(int c=0;c<3;c++) xv[1+c] = nr[32 + u*3 + c];
    #pragma unroll
    for(int c=0;c<5;c++) xv[4+c] = nr[128 + u*5 + c];
    float wr[11];
    #pragma unroll
    for(int p=0;p<11;p++) wr[p] = (wacc[e][p] + b2[p*32+u]) * cut[e];
    float out[9];
    #pragma unroll
    for(int q=0;q<9;q++) out[q] = 0.0f;
    const float* Me = &s_M[sub][e][0];
    #pragma unroll
    for(int p=0;p<11;p++){
      const int na = 2*PI_[p]+1;
      const int nc = 2*PK_[p]+1;
      const float wv = wr[p];
      #pragma unroll
      for(int a=0;a<na;a++){
        float xw = xv[AO_[PI_[p]]+a] * wv;
        #pragma unroll
        for(int c=0;c<nc;c++){
          out[AO_[PK_[p]]+c] += xw * Me[TOFF_[p] + a*nc + c];
        }
      }
    }
    float* ab = outp + (long)vdst[e]*288;
    atomicAdd(ab + u, 0.2f*out[0]);
    #pragma unroll
    for(int c=0;c<3;c++) atomicAdd(ab + 32 + u*3 + c, 0.2f*out[1+c]);
    #pragma unroll
    for(int c=0;c<5;c++) atomicAdd(ab + 128 + u*5 + c, 0.2f*out[4+c]);
  }
}

// ---------------- launch ----------------------------------------------------

extern "C" void kernel_launch(void* const* d_in, const int* in_sizes, int n_in,
                              void* d_out, int out_size, void* d_ws, size_t ws_size,
                              hipStream_t stream) {
  const float* nodes = (const float*)d_in[0];
  const float* pos   = (const float*)d_in[1];
  const int* src = (const int*)d_in[2];
  const int* dst = (const int*)d_in[3];
  const float* w1 = (const float*)d_in[4];
  const float* b1 = (const float*)d_in[5];
  const float* w2 = (const float*)d_in[6];
  const float* b2 = (const float*)d_in[7];

  const int E = in_sizes[2];
  float* outp = (float*)d_out;

  // d_out is poisoned 0xAA before every timed launch — zero it ourselves.
  hipMemsetAsync(outp, 0, (size_t)out_size * sizeof(float), stream);

  int nblocks = (E + SUBS*EPG - 1) / (SUBS*EPG);
  edge_kernel<<<nblocks, TPB, 0, stream>>>(nodes, pos, src, dst, w1, b1, w2, b2,
                                           outp, E, g_upload);
}

// Round 3
// 842.684 us; speedup vs baseline: 1.2348x; 1.2348x over previous
//
#include <hip/hip_runtime.h>
#include <hip/hip_bf16.h>
#include <cmath>
#include <complex>

#define TPB 256
#define SUBS 8
#define EPG 4
#define NM 115
#define NW3J 363
#define SCAN_T 1024
#define NBUCK 256

// ---------------- host-side W3J construction (exact port of reference) ------
namespace {

double fct(int n){ double r=1; for(int i=2;i<=n;i++) r*=i; return r; }

double su2_cg(int j1,int j2,int j3,int m1,int m2,int m3){
  if(m1+m2!=m3) return 0.0;
  double pref = std::sqrt((2*j3+1)*fct(j1+j2-j3)*fct(j1-j2+j3)*fct(-j1+j2+j3)/fct(j1+j2+j3+1));
  pref *= std::sqrt(fct(j3+m3)*fct(j3-m3)*fct(j1-m1)*fct(j1+m1)*fct(j2-m2)*fct(j2+m2));
  double s=0;
  for(int k=0;k<=j1+j2-j3;k++){
    int d0=k, d1=j1+j2-j3-k, d2=j1-m1-k, d3=j2+m2-k, d4=j3-j2+m1+k, d5=j3-j1-m2+k;
    if(d0<0||d1<0||d2<0||d3<0||d4<0||d5<0) continue;
    double t = 1.0/(fct(d0)*fct(d1)*fct(d2)*fct(d3)*fct(d4)*fct(d5));
    s += (k&1)? -t : t;
  }
  return pref*s;
}

typedef std::complex<double> cd;

void qmat(int l, cd q[5][5]){
  for(int i=0;i<5;i++) for(int j=0;j<5;j++) q[i][j] = cd(0,0);
  const double is2 = 1.0/std::sqrt(2.0);
  for(int m=-l;m<0;m++){ q[l+m][l-m] = cd(is2,0); q[l+m][l+m] = cd(0,-is2); }
  q[l][l] = cd(1,0);
  for(int m=1;m<=l;m++){ double sg = (m&1)? -1.0: 1.0; q[l+m][l+m] = cd(sg*is2,0); q[l+m][l-m] = cd(0, sg*is2); }
  cd ph(1,0), mi(0,-1);
  for(int t=0;t<l;t++) ph *= mi;
  for(int i=0;i<5;i++) for(int j=0;j<5;j++) q[i][j] *= ph;
}

void w3j_calc(int l1,int l2,int l3,double* out){
  int n1=2*l1+1,n2=2*l2+1,n3=2*l3+1;
  double C[5][5][5] = {};
  for(int m1=-l1;m1<=l1;m1++)for(int m2=-l2;m2<=l2;m2++)for(int m3=-l3;m3<=l3;m3++)
    C[l1+m1][l2+m2][l3+m3] = su2_cg(l1,l2,l3,m1,m2,m3);
  cd q1[5][5], q2[5][5], q3[5][5];
  qmat(l1,q1); qmat(l2,q2); qmat(l3,q3);
  double wr[125], wi[125];
  double nr=0, ni=0;
  for(int a=0;a<n1;a++)for(int b=0;b<n2;b++)for(int c=0;c<n3;c++){
    cd s(0,0);
    for(int i=0;i<n1;i++)for(int k=0;k<n2;k++)for(int m=0;m<n3;m++)
      s += q1[i][a]*q2[k][b]*std::conj(q3[m][c])*C[i][k][m];
    int idx = (a*n2+b)*n3+c;
    wr[idx]=s.real(); wi[idx]=s.imag();
    nr += s.real()*s.real(); ni += s.imag()*s.imag();
  }
  bool useR = std::sqrt(nr) >= std::sqrt(ni);
  double nn = std::sqrt(useR? nr: ni);
  for(int q=0;q<n1*n2*n3;q++) out[q] = (useR? wr[q]: wi[q])/nn;
}

struct UploadArg {
  float w3j[NW3J];        // PATH_W premultiplied, dense per path
  unsigned int meta[NM];  // per M-entry: woff | nc<<10 | nb<<14 | boff<<18
};

UploadArg g_upload;

struct BuildInit {
  BuildInit(){
    const int P[11][3] = {{0,0,0},{0,1,1},{0,2,2},{1,0,1},{1,1,0},{1,1,2},
                          {1,2,1},{2,0,2},{2,1,1},{2,2,0},{2,2,2}};
    const int cnt[3] = {3,4,4};
    const int AO[3] = {0,1,4};
    int off = 0, t = 0;
    for(int p=0;p<11;p++){
      int i=P[p][0], j=P[p][1], k=P[p][2];
      int na=2*i+1, nb=2*j+1, nc=2*k+1;
      double W[125];
      w3j_calc(i,j,k,W);
      double pw = std::sqrt((2.0*k+1.0)/(double)cnt[k]);
      for(int q=0;q<na*nb*nc;q++) g_upload.w3j[off+q] = (float)(W[q]*pw);
      for(int a=0;a<na;a++)
        for(int c=0;c<nc;c++)
          g_upload.meta[t++] = (unsigned)((off + a*nb*nc + c) | (nc<<10) | (nb<<14) | (AO[j]<<18));
      off += na*nb*nc;
    }
  }
};
BuildInit g_build_init;

} // namespace

// ---------------- CSR build kernels ----------------------------------------

__global__ void count_kernel(const int* __restrict__ dst, int* __restrict__ counts, int E){
  int e = blockIdx.x*blockDim.x + threadIdx.x;
  if(e < E) atomicAdd(&counts[dst[e]], 1);
}

__global__ __launch_bounds__(SCAN_T) void scan_kernel(const int* __restrict__ counts,
                                                      int* __restrict__ off,
                                                      int* __restrict__ cursor, int NN){
  __shared__ int part[SCAN_T];
  int t = threadIdx.x;
  int C = (NN + SCAN_T - 1)/SCAN_T;
  int base = t*C;
  int lim = min(base+C, NN);
  int s = 0;
  for(int i=base;i<lim;i++) s += counts[i];
  part[t] = s;
  __syncthreads();
  for(int d=1; d<SCAN_T; d<<=1){
    int v = (t>=d)? part[t-d] : 0;
    __syncthreads();
    part[t] += v;
    __syncthreads();
  }
  int run = part[t] - s;
  for(int i=base;i<lim;i++){ off[i]=run; cursor[i]=run; run += counts[i]; }
  if(t == SCAN_T-1) off[NN] = part[t];
}

__global__ void hist_kernel(const int* __restrict__ counts, int* __restrict__ hist, int NN){
  int n = blockIdx.x*blockDim.x + threadIdx.x;
  if(n < NN) atomicAdd(&hist[min(counts[n], NBUCK-1)], 1);
}

__global__ __launch_bounds__(NBUCK) void hscan_kernel(const int* __restrict__ hist,
                                                      int* __restrict__ bcur){
  __shared__ int part[NBUCK];
  int t = threadIdx.x;
  int s = hist[t];
  part[t] = s;
  __syncthreads();
  for(int d=1; d<NBUCK; d<<=1){
    int v = (t>=d)? part[t-d] : 0;
    __syncthreads();
    part[t] += v;
    __syncthreads();
  }
  bcur[t] = part[t] - s;   // exclusive
}

__global__ void node_scatter_kernel(const int* __restrict__ counts, int* __restrict__ bcur,
                                    int* __restrict__ node_order, int NN){
  int n = blockIdx.x*blockDim.x + threadIdx.x;
  if(n < NN){
    int p = atomicAdd(&bcur[min(counts[n], NBUCK-1)], 1);
    node_order[p] = n;
  }
}

__global__ void edge_scatter_kernel(const int* __restrict__ dst, int* __restrict__ cursor,
                                    int* __restrict__ eid, int E){
  int e = blockIdx.x*blockDim.x + threadIdx.x;
  if(e < E){
    int p = atomicAdd(&cursor[dst[e]], 1);
    eid[p] = e;
  }
}

// ---------------- main node-owned kernel ------------------------------------

__global__ __launch_bounds__(TPB) void node_kernel(
    const float* __restrict__ nodes,
    const float* __restrict__ pos,
    const int* __restrict__ src,
    const int* __restrict__ node_order,
    const int* __restrict__ off,
    const int* __restrict__ eid,
    const float* __restrict__ w1,
    const float* __restrict__ b1,
    const float* __restrict__ w2,
    const float* __restrict__ b2,
    float* __restrict__ outp,
    int NN,
    UploadArg up)
{
  __shared__ float s_w3j[NW3J];
  __shared__ float s_y[SUBS][EPG][12];
  __shared__ float s_h[SUBS][64][EPG];
  __shared__ float s_M[SUBS][EPG][NM+1];
  __shared__ int s_deg[SUBS];

  const int tid = threadIdx.x;
  const int u = tid & 31;
  const int sub = tid >> 5;

  for(int t = tid; t < NW3J; t += TPB) s_w3j[t] = up.w3j[t];

  const int nidx = blockIdx.x*SUBS + sub;
  int node = 0, deg = 0, start = 0;
  if(nidx < NN){
    node = node_order[nidx];
    start = off[node];
    deg = off[node+1] - start;
  }
  if(u == 0) s_deg[sub] = deg;
  __syncthreads();
  int maxdeg = 0;
  #pragma unroll
  for(int s2=0;s2<SUBS;s2++) maxdeg = max(maxdeg, s_deg[s2]);
  const int nch = (maxdeg + EPG - 1)/EPG;

  // hoisted per-lane loop invariants
  float b2r[11];
  #pragma unroll
  for(int p=0;p<11;p++) b2r[p] = b2[p*32+u];
  float b1l = b1[u], b1h = b1[u+32];
  float wcl[8], wch[8];
  #pragma unroll
  for(int k=0;k<8;k++){ wcl[k] = w1[k*64+u]; wch[k] = w1[k*64+u+32]; }
  const float dpx = pos[node*3+0], dpy = pos[node*3+1], dpz = pos[node*3+2];

  float accv[9];
  #pragma unroll
  for(int q=0;q<9;q++) accv[q] = 0.0f;

  constexpr int PI_[11]   = {0,0,0,1,1,1,1,2,2,2,2};
  constexpr int PK_[11]   = {0,1,2,1,0,2,1,2,1,0,2};
  constexpr int TOFF_[11] = {0,1,4,9,18,21,36,45,70,85,90};
  constexpr int AO_[3]    = {0,1,4};

  for(int ch=0; ch<nch; ch++){
    float bes[EPG][8];
    float cut[EPG];
    int vsrc[EPG];
    bool valid[EPG];

    #pragma unroll
    for(int e=0;e<EPG;e++){
      int ei = ch*EPG + e;
      bool v = (ei < deg);
      valid[e] = v;
      int eg = v ? eid[start + ei] : 0;
      int se = v ? src[eg] : node;   // invalid -> zero displacement, masked bessel
      vsrc[e] = se;
      float px = pos[se*3+0] - dpx;
      float py = pos[se*3+1] - dpy;
      float pz = pos[se*3+2] - dpz;
      float d2 = px*px + py*py + pz*pz;
      float d = sqrtf(d2);
      float inv = 1.0f / fmaxf(d, 1e-12f);
      float x = px*inv, y = py*inv, z = pz*inv;
      float yv[9];
      yv[0] = 1.0f;
      yv[1] = 1.7320508075688772f*y;
      yv[2] = 1.7320508075688772f*z;
      yv[3] = 1.7320508075688772f*x;
      yv[4] = 3.872983346207417f*x*y;
      yv[5] = 3.872983346207417f*y*z;
      yv[6] = 1.118033988749895f*(3.0f*z*z - 1.0f);
      yv[7] = 3.872983346207417f*x*z;
      yv[8] = 1.9364916731037085f*(x*x - y*y);
      #pragma unroll
      for(int q=0;q<9;q++) s_y[sub][e][q] = yv[q];  // all lanes same value
      // bessel via sin recurrence
      float tt = d * 0.2f;
      float st = (tt > 0.0f) ? tt : 1.0f;
      float msk = (tt > 0.0f && tt < 1.0f) ? 1.0f : 0.0f;
      float ang = 3.14159265358979323846f * tt;
      float s1 = __sinf(ang), c1 = __cosf(ang);
      float kk = 0.6324555320336759f * msk / st;
      float c2 = 2.0f*c1;
      float sp = 0.0f, sc = s1;
      bes[e][0] = kk*s1;
      #pragma unroll
      for(int n=1;n<8;n++){ float sn = c2*sc - sp; sp = sc; sc = sn; bes[e][n] = kk*sn; }
      float uu = d*0.25f;
      float u2 = uu*uu;
      float u5 = u2*u2*uu;
      float env = 1.0f - 6.0f*u5 + 5.0f*u5*uu;
      cut[e] = (d < 4.0f) ? env : 0.0f;
    }

    // MLP1
    #pragma unroll
    for(int half=0; half<2; half++){
      int j = u + 32*half;
      float hb = half ? b1h : b1l;
      float hh[EPG];
      #pragma unroll
      for(int e=0;e<EPG;e++){
        float a = hb;
        #pragma unroll
        for(int k=0;k<8;k++) a += bes[e][k]*(half ? wch[k] : wcl[k]);
        float sg = 1.0f/(1.0f + __expf(-a));
        hh[e] = a*sg;
      }
      float4 hv; hv.x = hh[0]; hv.y = hh[1]; hv.z = hh[2]; hv.w = hh[3];
      *(float4*)(&s_h[sub][j][0]) = hv;
    }
    __syncthreads();

    // M[a,c] = sum_b W3J[a,b,c]*y[b]
    #pragma unroll
    for(int w=0; w<4; w++){
      int t = u + 32*w;
      if(t < NM){
        unsigned int md = up.meta[t];
        int woff = md & 1023;
        int nc   = (md>>10) & 15;
        int nb   = (md>>14) & 15;
        int boff = (md>>18) & 15;
        #pragma unroll
        for(int e=0;e<EPG;e++){
          float s = 0.0f;
          for(int b=0;b<nb;b++) s += s_w3j[woff + b*nc] * s_y[sub][e][boff + b];
          s_M[sub][e][t] = s;
        }
      }
    }
    __syncthreads();

    // MLP2
    float wacc[EPG][11];
    #pragma unroll
    for(int e=0;e<EPG;e++)
      #pragma unroll
      for(int p=0;p<11;p++) wacc[e][p] = 0.0f;
    const float* wbase = w2 + u;
    for(int j=0;j<64;j++){
      float4 hv = *(const float4*)(&s_h[sub][j][0]);
      float sw[11];
      #pragma unroll
      for(int p=0;p<11;p++) sw[p] = wbase[j*352 + p*32];
      float hh[4]; hh[0]=hv.x; hh[1]=hv.y; hh[2]=hv.z; hh[3]=hv.w;
      #pragma unroll
      for(int e=0;e<EPG;e++)
        #pragma unroll
        for(int p=0;p<11;p++) wacc[e][p] += hh[e]*sw[p];
    }

    // Tensor product, accumulate into registers
    #pragma unroll
    for(int e=0;e<EPG;e++){
      if(!valid[e]) continue;
      const float* nr = nodes + (long)vsrc[e]*288;
      float xv[9];
      xv[0] = nr[u];
      #pragma unroll
      for(int c=0;c<3;c++) xv[1+c] = nr[32 + u*3 + c];
      #pragma unroll
      for(int c=0;c<5;c++) xv[4+c] = nr[128 + u*5 + c];
      float wr[11];
      #pragma unroll
      for(int p=0;p<11;p++) wr[p] = (wacc[e][p] + b2r[p]) * cut[e];
      const float* Me = &s_M[sub][e][0];
      #pragma unroll
      for(int p=0;p<11;p++){
        const int na = 2*PI_[p]+1;
        const int nc = 2*PK_[p]+1;
        const float wv = wr[p];
        #pragma unroll
        for(int a=0;a<na;a++){
          float xw = xv[AO_[PI_[p]]+a] * wv;
          #pragma unroll
          for(int c=0;c<nc;c++){
            accv[AO_[PK_[p]]+c] += xw * Me[TOFF_[p] + a*nc + c];
          }
        }
      }
    }
    __syncthreads();   // protect s_y/s_h/s_M before next iteration overwrites
  }

  if(nidx < NN){
    float* ob = outp + (long)node*288;
    ob[u] = 0.2f*accv[0];
    #pragma unroll
    for(int c=0;c<3;c++) ob[32 + u*3 + c] = 0.2f*accv[1+c];
    #pragma unroll
    for(int c=0;c<5;c++) ob[128 + u*5 + c] = 0.2f*accv[4+c];
  }
}

// ---------------- launch ----------------------------------------------------

extern "C" void kernel_launch(void* const* d_in, const int* in_sizes, int n_in,
                              void* d_out, int out_size, void* d_ws, size_t ws_size,
                              hipStream_t stream) {
  const float* nodes = (const float*)d_in[0];
  const float* pos   = (const float*)d_in[1];
  const int* src = (const int*)d_in[2];
  const int* dst = (const int*)d_in[3];
  const float* w1 = (const float*)d_in[4];
  const float* b1 = (const float*)d_in[5];
  const float* w2 = (const float*)d_in[6];
  const float* b2 = (const float*)d_in[7];

  const int E  = in_sizes[2];
  const int NN = in_sizes[0] / 288;
  float* outp = (float*)d_out;

  // workspace layout (ints)
  int* counts     = (int*)d_ws;            // NN   (must be zeroed)
  int* hist       = counts + NN;           // NBUCK (must be zeroed)
  int* off        = hist + NBUCK;          // NN+1
  int* cursor     = off + NN + 1;          // NN
  int* bcur       = cursor + NN;           // NBUCK
  int* node_order = bcur + NBUCK;          // NN
  int* eid        = node_order + NN;       // E

  hipMemsetAsync(counts, 0, (size_t)(NN + NBUCK)*sizeof(int), stream);

  count_kernel<<<(E+255)/256, 256, 0, stream>>>(dst, counts, E);
  scan_kernel<<<1, SCAN_T, 0, stream>>>(counts, off, cursor, NN);
  hist_kernel<<<(NN+255)/256, 256, 0, stream>>>(counts, hist, NN);
  hscan_kernel<<<1, NBUCK, 0, stream>>>(hist, bcur);
  node_scatter_kernel<<<(NN+255)/256, 256, 0, stream>>>(counts, bcur, node_order, NN);
  edge_scatter_kernel<<<(E+255)/256, 256, 0, stream>>>(dst, cursor, eid, E);

  int nblocks = (NN + SUBS - 1)/SUBS;
  node_kernel<<<nblocks, TPB, 0, stream>>>(nodes, pos, src, node_order, off, eid,
                                           w1, b1, w2, b2, outp, NN, g_upload);
}